// Round 2
// baseline (26513.156 us; speedup 1.0000x reference)
//
#include <hip/hip_runtime.h>

#define B_ 64
#define T_ 512
#define H_ 1024
#define I_ 256
#define O_ 256

// ---------------------------------------------------------------------------
// Tiled fp32 GEMM:  C[M][N] = A[M][KTOT] . Bw[N][KTOT]^T  (+ epilogue)
// EPI 0: C = acc + bias[n]
// EPI 1: C = scale[n]*(acc + bias[n]) - shift[n]
// ---------------------------------------------------------------------------
template <int KTOT, int EPI>
__global__ __launch_bounds__(256) void gemm_bt(
    const float* __restrict__ A, const float* __restrict__ Bw,
    const float* __restrict__ bias, const float* __restrict__ scale,
    const float* __restrict__ shift, float* __restrict__ C, int M, int N)
{
    __shared__ float As[64][68];
    __shared__ float Bs[64][68];
    const int tid = threadIdx.x;
    const int tx = tid & 15;   // n sub-block
    const int ty = tid >> 4;   // m sub-block
    const int NB = N >> 6;
    const int mblk = blockIdx.x / NB;
    const int nblk = blockIdx.x % NB;
    const int m0 = mblk << 6, n0 = nblk << 6;
    const int NC = KTOT / 64;

    float acc[4][4];
#pragma unroll
    for (int i = 0; i < 4; ++i) {
#pragma unroll
        for (int j = 0; j < 4; ++j) acc[i][j] = 0.f;
    }

    float4 ra[4], rb[4];
#pragma unroll
    for (int i = 0; i < 4; ++i) {
        int r = ty + 16 * i;
        ra[i] = *(const float4*)(A + (size_t)(m0 + r) * KTOT + tx * 4);
        rb[i] = *(const float4*)(Bw + (size_t)(n0 + r) * KTOT + tx * 4);
    }

    for (int c = 0; c < NC; ++c) {
#pragma unroll
        for (int i = 0; i < 4; ++i) {
            int r = ty + 16 * i;
            *(float4*)(&As[r][(tx ^ (r >> 2)) * 4]) = ra[i];
            *(float4*)(&Bs[r][(tx ^ (r >> 2)) * 4]) = rb[i];
        }
        __syncthreads();
        if (c + 1 < NC) {
            int kc = (c + 1) * 64;
#pragma unroll
            for (int i = 0; i < 4; ++i) {
                int r = ty + 16 * i;
                ra[i] = *(const float4*)(A + (size_t)(m0 + r) * KTOT + kc + tx * 4);
                rb[i] = *(const float4*)(Bw + (size_t)(n0 + r) * KTOT + kc + tx * 4);
            }
        }
#pragma unroll
        for (int kg = 0; kg < 16; ++kg) {
            float4 a4[4], b4[4];
#pragma unroll
            for (int i = 0; i < 4; ++i)
                a4[i] = *(const float4*)(&As[4 * ty + i][(kg ^ ty) * 4]);
#pragma unroll
            for (int j = 0; j < 4; ++j)
                b4[j] = *(const float4*)(&Bs[4 * tx + j][(kg ^ tx) * 4]);
#pragma unroll
            for (int i = 0; i < 4; ++i) {
#pragma unroll
                for (int j = 0; j < 4; ++j) {
                    acc[i][j] += a4[i].x * b4[j].x + a4[i].y * b4[j].y +
                                 a4[i].z * b4[j].z + a4[i].w * b4[j].w;
                }
            }
        }
        __syncthreads();
    }

    float4 bi4 = *(const float4*)(bias + n0 + tx * 4);
    float4 sc4, sh4;
    if (EPI == 1) {
        sc4 = *(const float4*)(scale + n0 + tx * 4);
        sh4 = *(const float4*)(shift + n0 + tx * 4);
    }
#pragma unroll
    for (int i = 0; i < 4; ++i) {
        float4 r;
        if (EPI == 0) {
            r.x = acc[i][0] + bi4.x;
            r.y = acc[i][1] + bi4.y;
            r.z = acc[i][2] + bi4.z;
            r.w = acc[i][3] + bi4.w;
        } else {
            r.x = sc4.x * (acc[i][0] + bi4.x) - sh4.x;
            r.y = sc4.y * (acc[i][1] + bi4.y) - sh4.y;
            r.z = sc4.z * (acc[i][2] + bi4.z) - sh4.z;
            r.w = sc4.w * (acc[i][3] + bi4.w) - sh4.w;
        }
        *(float4*)(C + (size_t)(m0 + 4 * ty + i) * N + n0 + 4 * tx) = r;
    }
}

// ---------------------------------------------------------------------------
// Recurrent kernel. 256 blocks x 256 threads, PLAIN launch.
// Co-residency by capacity: 128 KiB LDS -> exactly 1 block/CU, 256 blocks on
// 256 CUs. 4 domains x 64 WGs; domain d owns batches 16d..16d+15; WG w owns
// rows 16w..16w+15. W-slice LDS-resident for the whole scan; h staged per
// step. x_proj pre-written into hids[b][t][:], overwritten in place by h_t.
// Sync: monotonic per-WG flags, acquire loads + agent fences, timeout bail.
// ---------------------------------------------------------------------------
__global__ __launch_bounds__(256) void rnn_rec(
    const float* __restrict__ w_rec, const float* __restrict__ b_rec,
    float* __restrict__ hids, int* __restrict__ flags)
{
    __shared__ float Wl[16 * 1024];
    __shared__ float Hl[16 * 1024];
    const int tid = threadIdx.x;
    const int bid = blockIdx.x;
    const int wg = bid & 63;
    const int r0 = wg << 4;
    const int b0 = (bid >> 6) << 4;
    const int fbase = bid & ~63;

    // ---- preload W rows r0..r0+15, swizzled: pk = kg ^ ((kg>>3)&7) ^ ((r>>3)<<2)
    {
        const int r = tid >> 4, l = tid & 15;
        const float* src = w_rec + (size_t)(r0 + r) * H_;
        float* dst = Wl + r * 1024;
#pragma unroll
        for (int u = 0; u < 16; ++u) {
            int kg = u * 16 + l;
            float4 v = *(const float4*)(src + kg * 4);
            int pk = kg ^ ((kg >> 3) & 7) ^ ((r >> 3) << 2);
            *(float4*)(dst + pk * 4) = v;
        }
    }

    // epilogue mapping: output o = tid -> (b_local = tid>>4, r_local = tid&15)
    const int bl_e = tid >> 4, rl_e = tid & 15;
    const float brec = b_rec[r0 + rl_e];
    float* xcell = hids + ((size_t)(b0 + bl_e) * T_) * H_ + (r0 + rl_e);

    // compute mapping: tid = ks*8 + rb*4 + bb ; tile 4b x 8r, K split 32 ways
    const int ks = tid >> 3;        // 0..31, k-slice of 32
    const int rb = (tid >> 2) & 1;  // row block (8 rows)
    const int bb = tid & 3;         // batch block (4 batches)
    const int cW = (ks & 7) ^ (rb << 2);
    const int cH = (ks & 7) ^ (bb << 1);

    __syncthreads();

    for (int t = 0; t < T_; ++t) {
        float x = xcell[(size_t)t * H_];  // own x_proj cell (unique owner)
        float sum = 0.f;
        if (t > 0) {
            // ---- wait for all 64 WGs of this domain to finish step t-1
            if (tid < 64) {
                long long tstart = __builtin_amdgcn_s_memrealtime();
                for (;;) {
                    int f = __hip_atomic_load(&flags[fbase + tid], __ATOMIC_ACQUIRE,
                                              __HIP_MEMORY_SCOPE_AGENT);
                    if (__all(f >= t)) break;
                    __builtin_amdgcn_s_sleep(8);
                    // ~20ms bailout (memrealtime ~100 MHz): degrade to wrong
                    // answer instead of hang if co-residency ever fails
                    if (__builtin_amdgcn_s_memrealtime() - tstart > 2000000LL) break;
                }
            }
            __syncthreads();
            __threadfence();  // acquire: discard stale cached h before reading

            // ---- stage h_{t-1}[b0..b0+15][0..1023] into LDS (swizzled)
            {
                const int blr = tid >> 4, l = tid & 15;
                const float* hsrc = hids + ((size_t)(b0 + blr) * T_ + (t - 1)) * H_;
                float* hdst = Hl + blr * 1024;
#pragma unroll
                for (int u = 0; u < 16; ++u) {
                    int kg = u * 16 + l;
                    float4 v = *(const float4*)(hsrc + kg * 4);
                    int pk = kg ^ ((kg >> 3) & 7) ^ ((blr >> 2) << 1);
                    *(float4*)(hdst + pk * 4) = v;
                }
            }
            __syncthreads();

            // ---- partial dot products over this thread's 32-wide k slice
            float acc[4][8];
#pragma unroll
            for (int i = 0; i < 4; ++i) {
#pragma unroll
                for (int j = 0; j < 8; ++j) acc[i][j] = 0.f;
            }
#pragma unroll
            for (int j4 = 0; j4 < 8; ++j4) {
                const int sW = (j4 ^ cW) << 2;
                const int sH = (j4 ^ cH) << 2;
                float4 hv[4], wv[8];
#pragma unroll
                for (int i = 0; i < 4; ++i)
                    hv[i] = *(const float4*)(Hl + (bb * 4 + i) * 1024 + ks * 32 + sH);
#pragma unroll
                for (int i = 0; i < 8; ++i)
                    wv[i] = *(const float4*)(Wl + (rb * 8 + i) * 1024 + ks * 32 + sW);
#pragma unroll
                for (int bi = 0; bi < 4; ++bi) {
#pragma unroll
                    for (int ri = 0; ri < 8; ++ri) {
                        acc[bi][ri] += hv[bi].x * wv[ri].x + hv[bi].y * wv[ri].y +
                                       hv[bi].z * wv[ri].z + hv[bi].w * wv[ri].w;
                    }
                }
            }
            __syncthreads();  // Hl consumed -> reuse as reduction scratch

            float* scr = Hl;  // [32][259] layout, pad 259 to spread banks
#pragma unroll
            for (int bi = 0; bi < 4; ++bi) {
#pragma unroll
                for (int ri = 0; ri < 8; ++ri) {
                    int o = (bb * 4 + bi) * 16 + rb * 8 + ri;
                    scr[ks * 259 + o] = acc[bi][ri];
                }
            }
            __syncthreads();
            float s0 = 0.f, s1 = 0.f, s2 = 0.f, s3 = 0.f;
#pragma unroll
            for (int s = 0; s < 8; ++s) {
                s0 += scr[(4 * s + 0) * 259 + tid];
                s1 += scr[(4 * s + 1) * 259 + tid];
                s2 += scr[(4 * s + 2) * 259 + tid];
                s3 += scr[(4 * s + 3) * 259 + tid];
            }
            sum = (s0 + s1) + (s2 + s3);
        }

        float hnew = fmaxf(sum + brec + x, 0.f);
        xcell[(size_t)t * H_] = hnew;

        __threadfence();   // release: make h_t visible device-wide
        __syncthreads();   // all threads' stores done before flag
        if (tid == 0)
            __hip_atomic_store(&flags[bid], t + 1, __ATOMIC_RELEASE,
                               __HIP_MEMORY_SCOPE_AGENT);
    }
}

// ---------------------------------------------------------------------------
extern "C" void kernel_launch(void* const* d_in, const int* in_sizes, int n_in,
                              void* d_out, int out_size, void* d_ws, size_t ws_size,
                              hipStream_t stream)
{
    const float* inputs = (const float*)d_in[0];
    const float* w_rec  = (const float*)d_in[1];
    const float* b_rec  = (const float*)d_in[2];
    const float* w_in   = (const float*)d_in[3];
    const float* b_in   = (const float*)d_in[4];
    const float* w_out  = (const float*)d_in[5];
    const float* b_out  = (const float*)d_in[6];
    const float* scale  = (const float*)d_in[7];
    const float* shift  = (const float*)d_in[8];

    float* outs = (float*)d_out;                       // [B][T][O]
    float* hids = outs + (size_t)B_ * T_ * O_;         // [B][T][H]
    int* flags = (int*)d_ws;                           // 256 monotonic step counters

    hipMemsetAsync(d_ws, 0, 1024, stream);

    // K1: x_proj = inputs @ w_in^T + b_in  -> written into hids region
    gemm_bt<I_, 0><<<dim3((B_ * T_ / 64) * (H_ / 64)), dim3(256), 0, stream>>>(
        inputs, w_in, b_in, nullptr, nullptr, hids, B_ * T_, H_);

    // K2: recurrent scan — plain launch; co-residency by capacity (1 blk/CU x 256)
    rnn_rec<<<dim3(256), dim3(256), 0, stream>>>(w_rec, b_rec, hids, flags);

    // K3: outs = scale * (hids @ w_out^T + b_out) - shift
    gemm_bt<H_, 1><<<dim3((B_ * T_ / 64) * (O_ / 64)), dim3(256), 0, stream>>>(
        hids, w_out, b_out, scale, shift, outs, B_ * T_, O_);
}

// Round 3
// 8889.920 us; speedup vs baseline: 2.9824x; 2.9824x over previous
//
#include <hip/hip_runtime.h>

#define B_ 64
#define T_ 512
#define H_ 1024
#define I_ 256
#define O_ 256

// ---------------------------------------------------------------------------
// Tiled fp32 GEMM:  C[M][N] = A[M][KTOT] . Bw[N][KTOT]^T  (+ epilogue)
// EPI 0: C = acc + bias[n]
// EPI 1: C = scale[n]*(acc + bias[n]) - shift[n]
// ---------------------------------------------------------------------------
template <int KTOT, int EPI>
__global__ __launch_bounds__(256) void gemm_bt(
    const float* __restrict__ A, const float* __restrict__ Bw,
    const float* __restrict__ bias, const float* __restrict__ scale,
    const float* __restrict__ shift, float* __restrict__ C, int M, int N)
{
    __shared__ float As[64][68];
    __shared__ float Bs[64][68];
    const int tid = threadIdx.x;
    const int tx = tid & 15;   // n sub-block
    const int ty = tid >> 4;   // m sub-block
    const int NB = N >> 6;
    const int mblk = blockIdx.x / NB;
    const int nblk = blockIdx.x % NB;
    const int m0 = mblk << 6, n0 = nblk << 6;
    const int NC = KTOT / 64;

    float acc[4][4];
#pragma unroll
    for (int i = 0; i < 4; ++i) {
#pragma unroll
        for (int j = 0; j < 4; ++j) acc[i][j] = 0.f;
    }

    float4 ra[4], rb[4];
#pragma unroll
    for (int i = 0; i < 4; ++i) {
        int r = ty + 16 * i;
        ra[i] = *(const float4*)(A + (size_t)(m0 + r) * KTOT + tx * 4);
        rb[i] = *(const float4*)(Bw + (size_t)(n0 + r) * KTOT + tx * 4);
    }

    for (int c = 0; c < NC; ++c) {
#pragma unroll
        for (int i = 0; i < 4; ++i) {
            int r = ty + 16 * i;
            *(float4*)(&As[r][(tx ^ (r >> 2)) * 4]) = ra[i];
            *(float4*)(&Bs[r][(tx ^ (r >> 2)) * 4]) = rb[i];
        }
        __syncthreads();
        if (c + 1 < NC) {
            int kc = (c + 1) * 64;
#pragma unroll
            for (int i = 0; i < 4; ++i) {
                int r = ty + 16 * i;
                ra[i] = *(const float4*)(A + (size_t)(m0 + r) * KTOT + kc + tx * 4);
                rb[i] = *(const float4*)(Bw + (size_t)(n0 + r) * KTOT + kc + tx * 4);
            }
        }
#pragma unroll
        for (int kg = 0; kg < 16; ++kg) {
            float4 a4[4], b4[4];
#pragma unroll
            for (int i = 0; i < 4; ++i)
                a4[i] = *(const float4*)(&As[4 * ty + i][(kg ^ ty) * 4]);
#pragma unroll
            for (int j = 0; j < 4; ++j)
                b4[j] = *(const float4*)(&Bs[4 * tx + j][(kg ^ tx) * 4]);
#pragma unroll
            for (int i = 0; i < 4; ++i) {
#pragma unroll
                for (int j = 0; j < 4; ++j) {
                    acc[i][j] += a4[i].x * b4[j].x + a4[i].y * b4[j].y +
                                 a4[i].z * b4[j].z + a4[i].w * b4[j].w;
                }
            }
        }
        __syncthreads();
    }

    float4 bi4 = *(const float4*)(bias + n0 + tx * 4);
    float4 sc4, sh4;
    if (EPI == 1) {
        sc4 = *(const float4*)(scale + n0 + tx * 4);
        sh4 = *(const float4*)(shift + n0 + tx * 4);
    }
#pragma unroll
    for (int i = 0; i < 4; ++i) {
        float4 r;
        if (EPI == 0) {
            r.x = acc[i][0] + bi4.x;
            r.y = acc[i][1] + bi4.y;
            r.z = acc[i][2] + bi4.z;
            r.w = acc[i][3] + bi4.w;
        } else {
            r.x = sc4.x * (acc[i][0] + bi4.x) - sh4.x;
            r.y = sc4.y * (acc[i][1] + bi4.y) - sh4.y;
            r.z = sc4.z * (acc[i][2] + bi4.z) - sh4.z;
            r.w = sc4.w * (acc[i][3] + bi4.w) - sh4.w;
        }
        *(float4*)(C + (size_t)(m0 + 4 * ty + i) * N + n0 + 4 * tx) = r;
    }
}

// ---------------------------------------------------------------------------
// Recurrent kernel. 256 blocks x 256 threads, plain launch; co-residency by
// capacity (128 KiB LDS -> 1 block/CU, 256 blocks on 256 CUs).
// 4 domains x 64 WGs. Domain d owns batches 16d..16d+15; WG w owns rows
// 16w..16w+15. W-slice LDS-resident for the whole scan.
//
// FENCE-FREE exchange protocol (no __threadfence, no acquire spins):
//  - h stores: relaxed AGENT-scope atomic stores -> write-through to LLC
//    (no buffer_wbl2 L2 walks).
//  - ordering: per-wave s_waitcnt vmcnt(0) + __syncthreads, then ONE relaxed
//    atomicAdd per WG to a per-domain counter in d_ws.
//  - consumer: lane 0 spins on relaxed counter load (no buffer_inv per poll);
//    h staged via relaxed AGENT 8B atomic loads, which bypass L1/L2 and read
//    the LLC directly (stale-L1 hazard from the x prefetch is structurally
//    avoided: h is never read through plain loads).
// ---------------------------------------------------------------------------
__global__ __launch_bounds__(256) void rnn_rec(
    const float* __restrict__ w_rec, const float* __restrict__ b_rec,
    float* __restrict__ hids, unsigned* __restrict__ flags)
{
    __shared__ float Wl[16 * 1024];
    __shared__ float Hl[16 * 1024];
    const int tid = threadIdx.x;
    const int bid = blockIdx.x;
    const int wg = bid & 63;
    const int r0 = wg << 4;
    const int b0 = (bid >> 6) << 4;
    unsigned* ctr = flags + ((bid >> 6) << 6);  // per-domain counter, 256B apart

    // ---- preload W rows r0..r0+15, swizzled: pk = kg ^ ((kg>>3)&7) ^ ((r>>3)<<2)
    {
        const int r = tid >> 4, l = tid & 15;
        const float* src = w_rec + (size_t)(r0 + r) * H_;
        float* dst = Wl + r * 1024;
#pragma unroll
        for (int u = 0; u < 16; ++u) {
            int kg = u * 16 + l;
            float4 v = *(const float4*)(src + kg * 4);
            int pk = kg ^ ((kg >> 3) & 7) ^ ((r >> 3) << 2);
            *(float4*)(dst + pk * 4) = v;
        }
    }

    // epilogue mapping: output o = tid -> (b_local = tid>>4, r_local = tid&15)
    const int bl_e = tid >> 4, rl_e = tid & 15;
    const float brec = b_rec[r0 + rl_e];
    float* xcell = hids + ((size_t)(b0 + bl_e) * T_) * H_ + (r0 + rl_e);

    // compute mapping: tid = ks*8 + rb*4 + bb ; tile 4b x 8r, K split 32 ways
    const int ks = tid >> 3;        // 0..31, k-slice of 32
    const int rb = (tid >> 2) & 1;  // row block (8 rows)
    const int bb = tid & 3;         // batch block (4 batches)
    const int cW = (ks & 7) ^ (rb << 2);
    const int cH = (ks & 7) ^ (bb << 1);

    __syncthreads();

    for (int t = 0; t < T_; ++t) {
        float x = xcell[(size_t)t * H_];  // own x_proj cell (unique owner; K1 data)
        float sum = 0.f;
        if (t > 0) {
            // ---- wait: all 64 WGs of this domain finished step t-1
            if (tid == 0) {
                const unsigned tgt = 64u * (unsigned)t;
                long long ts = __builtin_amdgcn_s_memrealtime();
                while (__hip_atomic_load(ctr, __ATOMIC_RELAXED,
                                         __HIP_MEMORY_SCOPE_AGENT) < tgt) {
                    // ~100ms hang bailout (memrealtime ~100 MHz)
                    if (__builtin_amdgcn_s_memrealtime() - ts > 10000000LL) break;
                }
            }
            __syncthreads();

            // ---- stage h_{t-1}[b0..b0+15][:] into LDS via LLC-coherent 8B loads
            {
                const int blr = tid >> 4, l = tid & 15;
                const unsigned long long* hq = (const unsigned long long*)(
                    hids + ((size_t)(b0 + blr) * T_ + (t - 1)) * H_);
                float* hdst = Hl + blr * 1024;
#pragma unroll
                for (int u = 0; u < 32; ++u) {
                    int p = u * 16 + l;              // 8B pair index, 0..511
                    unsigned long long v = __hip_atomic_load(
                        (unsigned long long*)&hq[p], __ATOMIC_RELAXED,
                        __HIP_MEMORY_SCOPE_AGENT);
                    int kg = p >> 1;
                    int pk = kg ^ ((kg >> 3) & 7) ^ ((blr >> 2) << 1);
                    *(unsigned long long*)(hdst + pk * 4 + (p & 1) * 2) = v;
                }
            }
            __syncthreads();

            // ---- partial dot products over this thread's 32-wide k slice
            float acc[4][8];
#pragma unroll
            for (int i = 0; i < 4; ++i) {
#pragma unroll
                for (int j = 0; j < 8; ++j) acc[i][j] = 0.f;
            }
#pragma unroll
            for (int j4 = 0; j4 < 8; ++j4) {
                const int sW = (j4 ^ cW) << 2;
                const int sH = (j4 ^ cH) << 2;
                float4 hv[4], wv[8];
#pragma unroll
                for (int i = 0; i < 4; ++i)
                    hv[i] = *(const float4*)(Hl + (bb * 4 + i) * 1024 + ks * 32 + sH);
#pragma unroll
                for (int i = 0; i < 8; ++i)
                    wv[i] = *(const float4*)(Wl + (rb * 8 + i) * 1024 + ks * 32 + sW);
#pragma unroll
                for (int bi = 0; bi < 4; ++bi) {
#pragma unroll
                    for (int ri = 0; ri < 8; ++ri) {
                        acc[bi][ri] += hv[bi].x * wv[ri].x + hv[bi].y * wv[ri].y +
                                       hv[bi].z * wv[ri].z + hv[bi].w * wv[ri].w;
                    }
                }
            }
            __syncthreads();  // Hl consumed -> reuse as reduction scratch

            float* scr = Hl;  // [32][259] layout, pad 259 to spread banks
#pragma unroll
            for (int bi = 0; bi < 4; ++bi) {
#pragma unroll
                for (int ri = 0; ri < 8; ++ri) {
                    int o = (bb * 4 + bi) * 16 + rb * 8 + ri;
                    scr[ks * 259 + o] = acc[bi][ri];
                }
            }
            __syncthreads();
            float s0 = 0.f, s1 = 0.f, s2 = 0.f, s3 = 0.f;
#pragma unroll
            for (int s = 0; s < 8; ++s) {
                s0 += scr[(4 * s + 0) * 259 + tid];
                s1 += scr[(4 * s + 1) * 259 + tid];
                s2 += scr[(4 * s + 2) * 259 + tid];
                s3 += scr[(4 * s + 3) * 259 + tid];
            }
            sum = (s0 + s1) + (s2 + s3);
        }

        float hnew = fmaxf(sum + brec + x, 0.f);
        // write-through to LLC (relaxed agent atomic store; no cache flush needed)
        __hip_atomic_store(&xcell[(size_t)t * H_], hnew, __ATOMIC_RELAXED,
                           __HIP_MEMORY_SCOPE_AGENT);

        // per-wave drain to LLC, then block-wide join, then one counter bump
        asm volatile("s_waitcnt vmcnt(0)" ::: "memory");
        __syncthreads();
        if (tid == 0)
            __hip_atomic_fetch_add(ctr, 1u, __ATOMIC_RELAXED,
                                   __HIP_MEMORY_SCOPE_AGENT);
    }
}

// ---------------------------------------------------------------------------
extern "C" void kernel_launch(void* const* d_in, const int* in_sizes, int n_in,
                              void* d_out, int out_size, void* d_ws, size_t ws_size,
                              hipStream_t stream)
{
    const float* inputs = (const float*)d_in[0];
    const float* w_rec  = (const float*)d_in[1];
    const float* b_rec  = (const float*)d_in[2];
    const float* w_in   = (const float*)d_in[3];
    const float* b_in   = (const float*)d_in[4];
    const float* w_out  = (const float*)d_in[5];
    const float* b_out  = (const float*)d_in[6];
    const float* scale  = (const float*)d_in[7];
    const float* shift  = (const float*)d_in[8];

    float* outs = (float*)d_out;                       // [B][T][O]
    float* hids = outs + (size_t)B_ * T_ * O_;         // [B][T][H]
    unsigned* flags = (unsigned*)d_ws;                 // 4 per-domain counters

    hipMemsetAsync(d_ws, 0, 1024, stream);

    // K1: x_proj = inputs @ w_in^T + b_in  -> written into hids region
    gemm_bt<I_, 0><<<dim3((B_ * T_ / 64) * (H_ / 64)), dim3(256), 0, stream>>>(
        inputs, w_in, b_in, nullptr, nullptr, hids, B_ * T_, H_);

    // K2: recurrent scan — plain launch; co-residency by capacity (1 blk/CU x 256)
    rnn_rec<<<dim3(256), dim3(256), 0, stream>>>(w_rec, b_rec, hids, flags);

    // K3: outs = scale * (hids @ w_out^T + b_out) - shift
    gemm_bt<H_, 1><<<dim3((B_ * T_ / 64) * (O_ / 64)), dim3(256), 0, stream>>>(
        hids, w_out, b_out, scale, shift, outs, B_ * T_, O_);
}

// Round 4
// 4768.315 us; speedup vs baseline: 5.5603x; 1.8644x over previous
//
#include <hip/hip_runtime.h>

#define B_ 64
#define T_ 512
#define H_ 1024
#define I_ 256
#define O_ 256

// ---------------------------------------------------------------------------
// Tiled fp32 GEMM:  C[M][N] = A[M][KTOT] . Bw[N][KTOT]^T  (+ epilogue)
// EPI 0: C = acc + bias[n]
// EPI 1: C = scale[n]*(acc + bias[n]) - shift[n]
// ---------------------------------------------------------------------------
template <int KTOT, int EPI>
__global__ __launch_bounds__(256) void gemm_bt(
    const float* __restrict__ A, const float* __restrict__ Bw,
    const float* __restrict__ bias, const float* __restrict__ scale,
    const float* __restrict__ shift, float* __restrict__ C, int M, int N)
{
    __shared__ float As[64][68];
    __shared__ float Bs[64][68];
    const int tid = threadIdx.x;
    const int tx = tid & 15;   // n sub-block
    const int ty = tid >> 4;   // m sub-block
    const int NB = N >> 6;
    const int mblk = blockIdx.x / NB;
    const int nblk = blockIdx.x % NB;
    const int m0 = mblk << 6, n0 = nblk << 6;
    const int NC = KTOT / 64;

    float acc[4][4];
#pragma unroll
    for (int i = 0; i < 4; ++i) {
#pragma unroll
        for (int j = 0; j < 4; ++j) acc[i][j] = 0.f;
    }

    float4 ra[4], rb[4];
#pragma unroll
    for (int i = 0; i < 4; ++i) {
        int r = ty + 16 * i;
        ra[i] = *(const float4*)(A + (size_t)(m0 + r) * KTOT + tx * 4);
        rb[i] = *(const float4*)(Bw + (size_t)(n0 + r) * KTOT + tx * 4);
    }

    for (int c = 0; c < NC; ++c) {
#pragma unroll
        for (int i = 0; i < 4; ++i) {
            int r = ty + 16 * i;
            *(float4*)(&As[r][(tx ^ (r >> 2)) * 4]) = ra[i];
            *(float4*)(&Bs[r][(tx ^ (r >> 2)) * 4]) = rb[i];
        }
        __syncthreads();
        if (c + 1 < NC) {
            int kc = (c + 1) * 64;
#pragma unroll
            for (int i = 0; i < 4; ++i) {
                int r = ty + 16 * i;
                ra[i] = *(const float4*)(A + (size_t)(m0 + r) * KTOT + kc + tx * 4);
                rb[i] = *(const float4*)(Bw + (size_t)(n0 + r) * KTOT + kc + tx * 4);
            }
        }
#pragma unroll
        for (int kg = 0; kg < 16; ++kg) {
            float4 a4[4], b4[4];
#pragma unroll
            for (int i = 0; i < 4; ++i)
                a4[i] = *(const float4*)(&As[4 * ty + i][(kg ^ ty) * 4]);
#pragma unroll
            for (int j = 0; j < 4; ++j)
                b4[j] = *(const float4*)(&Bs[4 * tx + j][(kg ^ tx) * 4]);
#pragma unroll
            for (int i = 0; i < 4; ++i) {
#pragma unroll
                for (int j = 0; j < 4; ++j) {
                    acc[i][j] += a4[i].x * b4[j].x + a4[i].y * b4[j].y +
                                 a4[i].z * b4[j].z + a4[i].w * b4[j].w;
                }
            }
        }
        __syncthreads();
    }

    float4 bi4 = *(const float4*)(bias + n0 + tx * 4);
    float4 sc4, sh4;
    if (EPI == 1) {
        sc4 = *(const float4*)(scale + n0 + tx * 4);
        sh4 = *(const float4*)(shift + n0 + tx * 4);
    }
#pragma unroll
    for (int i = 0; i < 4; ++i) {
        float4 r;
        if (EPI == 0) {
            r.x = acc[i][0] + bi4.x;
            r.y = acc[i][1] + bi4.y;
            r.z = acc[i][2] + bi4.z;
            r.w = acc[i][3] + bi4.w;
        } else {
            r.x = sc4.x * (acc[i][0] + bi4.x) - sh4.x;
            r.y = sc4.y * (acc[i][1] + bi4.y) - sh4.y;
            r.z = sc4.z * (acc[i][2] + bi4.z) - sh4.z;
            r.w = sc4.w * (acc[i][3] + bi4.w) - sh4.w;
        }
        *(float4*)(C + (size_t)(m0 + 4 * ty + i) * N + n0 + 4 * tx) = r;
    }
}

// ---------------------------------------------------------------------------
// Recurrent kernel. 256 blocks x 256 threads, plain launch; co-residency by
// capacity (128 KiB LDS -> 1 block/CU, 256 blocks on 256 CUs).
// 4 domains x 64 WGs. Domain d owns batches 16d..16d+15; WG w owns rows
// 16w..16w+15. W-slice LDS-resident for the whole scan.
//
// Exchange protocol (no fences):
//  - h stores: relaxed AGENT atomic stores -> write-through to LLC, no-alloc.
//  - own x_proj cell read: relaxed AGENT atomic 4B load (L1/L2 BYPASS) --
//    this is what keeps (b,t) lines out of our caches before peers overwrite
//    them, making the staging reads below safe.
//  - ordering: per-wave s_waitcnt vmcnt(0) + __syncthreads, then ONE relaxed
//    atomicAdd per WG to a per-domain counter.
//  - consumer: lane 0 spins on relaxed counter load; h_{t-1} then staged with
//    PLAIN cached float4 loads (L2-served broadcast). Safe: no cache holds
//    any (b,t-1) line from before the sync point (x reads bypass, staging at
//    t-1 touched (b,t-2) only, stores are no-allocate write-through, K1-era
//    lines were invalidated at dispatch boundary).
// ---------------------------------------------------------------------------
__global__ __launch_bounds__(256) void rnn_rec(
    const float* __restrict__ w_rec, const float* __restrict__ b_rec,
    float* __restrict__ hids, unsigned* __restrict__ flags)
{
    __shared__ float Wl[16 * 1024];
    __shared__ float Hl[16 * 1024];
    const int tid = threadIdx.x;
    const int bid = blockIdx.x;
    const int wg = bid & 63;
    const int r0 = wg << 4;
    const int b0 = (bid >> 6) << 4;
    unsigned* ctr = flags + ((bid >> 6) << 6);  // per-domain counter, 256B apart

    // ---- preload W rows r0..r0+15, swizzled: pk = kg ^ ((kg>>3)&7) ^ ((r>>3)<<2)
    {
        const int r = tid >> 4, l = tid & 15;
        const float* src = w_rec + (size_t)(r0 + r) * H_;
        float* dst = Wl + r * 1024;
#pragma unroll
        for (int u = 0; u < 16; ++u) {
            int kg = u * 16 + l;
            float4 v = *(const float4*)(src + kg * 4);
            int pk = kg ^ ((kg >> 3) & 7) ^ ((r >> 3) << 2);
            *(float4*)(dst + pk * 4) = v;
        }
    }

    // epilogue mapping: output o = tid -> (b_local = tid>>4, r_local = tid&15)
    const int bl_e = tid >> 4, rl_e = tid & 15;
    const float brec = b_rec[r0 + rl_e];
    float* xcell = hids + ((size_t)(b0 + bl_e) * T_) * H_ + (r0 + rl_e);

    // compute mapping: tid = ks*8 + rb*4 + bb ; tile 4b x 8r, K split 32 ways
    const int ks = tid >> 3;        // 0..31, k-slice of 32
    const int rb = (tid >> 2) & 1;  // row block (8 rows)
    const int bb = tid & 3;         // batch block (4 batches)
    const int cW = (ks & 7) ^ (rb << 2);
    const int cH = (ks & 7) ^ (bb << 1);
    // reduction read index: un-swizzle the (o ^ bb<<3) scratch layout
    const int rd_idx = tid ^ (((tid >> 6) & 3) << 3);

    __syncthreads();

    for (int t = 0; t < T_; ++t) {
        // own x_proj cell -- BYPASS load (keeps (b,t) lines out of L1/L2)
        float x = __hip_atomic_load(&xcell[(size_t)t * H_], __ATOMIC_RELAXED,
                                    __HIP_MEMORY_SCOPE_AGENT);
        float sum = 0.f;
        if (t > 0) {
            // ---- wait: all 64 WGs of this domain finished step t-1
            if (tid == 0) {
                const unsigned tgt = 64u * (unsigned)t;
                long long ts = __builtin_amdgcn_s_memrealtime();
                while (__hip_atomic_load(ctr, __ATOMIC_RELAXED,
                                         __HIP_MEMORY_SCOPE_AGENT) < tgt) {
                    // ~100ms hang bailout (memrealtime ~100 MHz)
                    if (__builtin_amdgcn_s_memrealtime() - ts > 10000000LL) break;
                }
            }
            __syncthreads();

            // ---- stage h_{t-1}[b0..b0+15][:] into LDS, PLAIN cached float4
            {
                const int blr = tid >> 4, l = tid & 15;
                const float* hsrc = hids + ((size_t)(b0 + blr) * T_ + (t - 1)) * H_;
                float* hdst = Hl + blr * 1024;
#pragma unroll
                for (int u = 0; u < 16; ++u) {
                    int kg = u * 16 + l;
                    float4 v = *(const float4*)(hsrc + kg * 4);
                    int pk = kg ^ ((kg >> 3) & 7) ^ ((blr >> 2) << 1);
                    *(float4*)(hdst + pk * 4) = v;
                }
            }
            __syncthreads();

            // ---- partial dot products over this thread's 32-wide k slice
            float acc[4][8];
#pragma unroll
            for (int i = 0; i < 4; ++i) {
#pragma unroll
                for (int j = 0; j < 8; ++j) acc[i][j] = 0.f;
            }
#pragma unroll
            for (int j4 = 0; j4 < 8; ++j4) {
                const int sW = (j4 ^ cW) << 2;
                const int sH = (j4 ^ cH) << 2;
                float4 hv[4], wv[8];
#pragma unroll
                for (int i = 0; i < 4; ++i)
                    hv[i] = *(const float4*)(Hl + (bb * 4 + i) * 1024 + ks * 32 + sH);
#pragma unroll
                for (int i = 0; i < 8; ++i)
                    wv[i] = *(const float4*)(Wl + (rb * 8 + i) * 1024 + ks * 32 + sW);
#pragma unroll
                for (int bi = 0; bi < 4; ++bi) {
#pragma unroll
                    for (int ri = 0; ri < 8; ++ri) {
                        acc[bi][ri] += hv[bi].x * wv[ri].x + hv[bi].y * wv[ri].y +
                                       hv[bi].z * wv[ri].z + hv[bi].w * wv[ri].w;
                    }
                }
            }
            __syncthreads();  // Hl consumed -> reuse as reduction scratch

            float* scr = Hl;  // [32][259]; write swizzle o^(bb<<3) -> 2-way free
#pragma unroll
            for (int bi = 0; bi < 4; ++bi) {
#pragma unroll
                for (int ri = 0; ri < 8; ++ri) {
                    int o = ((bb * 4 + bi) * 16 + rb * 8 + ri) ^ (bb << 3);
                    scr[ks * 259 + o] = acc[bi][ri];
                }
            }
            __syncthreads();
            float s0 = 0.f, s1 = 0.f, s2 = 0.f, s3 = 0.f;
#pragma unroll
            for (int s = 0; s < 8; ++s) {
                s0 += scr[(4 * s + 0) * 259 + rd_idx];
                s1 += scr[(4 * s + 1) * 259 + rd_idx];
                s2 += scr[(4 * s + 2) * 259 + rd_idx];
                s3 += scr[(4 * s + 3) * 259 + rd_idx];
            }
            sum = (s0 + s1) + (s2 + s3);
        }

        float hnew = fmaxf(sum + brec + x, 0.f);
        // write-through to LLC (relaxed agent atomic store; no-allocate)
        __hip_atomic_store(&xcell[(size_t)t * H_], hnew, __ATOMIC_RELAXED,
                           __HIP_MEMORY_SCOPE_AGENT);

        // per-wave drain to LLC, then block-wide join, then one counter bump
        asm volatile("s_waitcnt vmcnt(0)" ::: "memory");
        __syncthreads();
        if (tid == 0)
            __hip_atomic_fetch_add(ctr, 1u, __ATOMIC_RELAXED,
                                   __HIP_MEMORY_SCOPE_AGENT);
    }
}

// ---------------------------------------------------------------------------
extern "C" void kernel_launch(void* const* d_in, const int* in_sizes, int n_in,
                              void* d_out, int out_size, void* d_ws, size_t ws_size,
                              hipStream_t stream)
{
    const float* inputs = (const float*)d_in[0];
    const float* w_rec  = (const float*)d_in[1];
    const float* b_rec  = (const float*)d_in[2];
    const float* w_in   = (const float*)d_in[3];
    const float* b_in   = (const float*)d_in[4];
    const float* w_out  = (const float*)d_in[5];
    const float* b_out  = (const float*)d_in[6];
    const float* scale  = (const float*)d_in[7];
    const float* shift  = (const float*)d_in[8];

    float* outs = (float*)d_out;                       // [B][T][O]
    float* hids = outs + (size_t)B_ * T_ * O_;         // [B][T][H]
    unsigned* flags = (unsigned*)d_ws;                 // 4 per-domain counters

    hipMemsetAsync(d_ws, 0, 1024, stream);

    // K1: x_proj = inputs @ w_in^T + b_in  -> written into hids region
    gemm_bt<I_, 0><<<dim3((B_ * T_ / 64) * (H_ / 64)), dim3(256), 0, stream>>>(
        inputs, w_in, b_in, nullptr, nullptr, hids, B_ * T_, H_);

    // K2: recurrent scan — plain launch; co-residency by capacity (1 blk/CU x 256)
    rnn_rec<<<dim3(256), dim3(256), 0, stream>>>(w_rec, b_rec, hids, flags);

    // K3: outs = scale * (hids @ w_out^T + b_out) - shift
    gemm_bt<H_, 1><<<dim3((B_ * T_ / 64) * (O_ / 64)), dim3(256), 0, stream>>>(
        hids, w_out, b_out, scale, shift, outs, B_ * T_, O_);
}

// Round 6
// 4574.401 us; speedup vs baseline: 5.7960x; 1.0424x over previous
//
#include <hip/hip_runtime.h>

#define B_ 64
#define T_ 512
#define H_ 1024
#define I_ 256
#define O_ 256

// ---------------------------------------------------------------------------
// Tiled fp32 GEMM:  C[M][N] = A[M][KTOT] . Bw[N][KTOT]^T  (+ epilogue)
// EPI 0: C = acc + bias[n]
// EPI 1: C = scale[n]*(acc + bias[n]) - shift[n]
// ---------------------------------------------------------------------------
template <int KTOT, int EPI>
__global__ __launch_bounds__(256) void gemm_bt(
    const float* __restrict__ A, const float* __restrict__ Bw,
    const float* __restrict__ bias, const float* __restrict__ scale,
    const float* __restrict__ shift, float* __restrict__ C, int M, int N)
{
    __shared__ float As[64][68];
    __shared__ float Bs[64][68];
    const int tid = threadIdx.x;
    const int tx = tid & 15;   // n sub-block
    const int ty = tid >> 4;   // m sub-block
    const int NB = N >> 6;
    const int mblk = blockIdx.x / NB;
    const int nblk = blockIdx.x % NB;
    const int m0 = mblk << 6, n0 = nblk << 6;
    const int NC = KTOT / 64;

    float acc[4][4];
#pragma unroll
    for (int i = 0; i < 4; ++i) {
#pragma unroll
        for (int j = 0; j < 4; ++j) acc[i][j] = 0.f;
    }

    float4 ra[4], rb[4];
#pragma unroll
    for (int i = 0; i < 4; ++i) {
        int r = ty + 16 * i;
        ra[i] = *(const float4*)(A + (size_t)(m0 + r) * KTOT + tx * 4);
        rb[i] = *(const float4*)(Bw + (size_t)(n0 + r) * KTOT + tx * 4);
    }

    for (int c = 0; c < NC; ++c) {
#pragma unroll
        for (int i = 0; i < 4; ++i) {
            int r = ty + 16 * i;
            *(float4*)(&As[r][(tx ^ (r >> 2)) * 4]) = ra[i];
            *(float4*)(&Bs[r][(tx ^ (r >> 2)) * 4]) = rb[i];
        }
        __syncthreads();
        if (c + 1 < NC) {
            int kc = (c + 1) * 64;
#pragma unroll
            for (int i = 0; i < 4; ++i) {
                int r = ty + 16 * i;
                ra[i] = *(const float4*)(A + (size_t)(m0 + r) * KTOT + kc + tx * 4);
                rb[i] = *(const float4*)(Bw + (size_t)(n0 + r) * KTOT + kc + tx * 4);
            }
        }
#pragma unroll
        for (int kg = 0; kg < 16; ++kg) {
            float4 a4[4], b4[4];
#pragma unroll
            for (int i = 0; i < 4; ++i)
                a4[i] = *(const float4*)(&As[4 * ty + i][(kg ^ ty) * 4]);
#pragma unroll
            for (int j = 0; j < 4; ++j)
                b4[j] = *(const float4*)(&Bs[4 * tx + j][(kg ^ tx) * 4]);
#pragma unroll
            for (int i = 0; i < 4; ++i) {
#pragma unroll
                for (int j = 0; j < 4; ++j) {
                    acc[i][j] += a4[i].x * b4[j].x + a4[i].y * b4[j].y +
                                 a4[i].z * b4[j].z + a4[i].w * b4[j].w;
                }
            }
        }
        __syncthreads();
    }

    float4 bi4 = *(const float4*)(bias + n0 + tx * 4);
    float4 sc4, sh4;
    if (EPI == 1) {
        sc4 = *(const float4*)(scale + n0 + tx * 4);
        sh4 = *(const float4*)(shift + n0 + tx * 4);
    }
#pragma unroll
    for (int i = 0; i < 4; ++i) {
        float4 r;
        if (EPI == 0) {
            r.x = acc[i][0] + bi4.x;
            r.y = acc[i][1] + bi4.y;
            r.z = acc[i][2] + bi4.z;
            r.w = acc[i][3] + bi4.w;
        } else {
            r.x = sc4.x * (acc[i][0] + bi4.x) - sh4.x;
            r.y = sc4.y * (acc[i][1] + bi4.y) - sh4.y;
            r.z = sc4.z * (acc[i][2] + bi4.z) - sh4.z;
            r.w = sc4.w * (acc[i][3] + bi4.w) - sh4.w;
        }
        *(float4*)(C + (size_t)(m0 + 4 * ty + i) * N + n0 + 4 * tx) = r;
    }
}

// ---------------------------------------------------------------------------
// Recurrent kernel. 256 blocks x 256 threads, plain launch; co-residency by
// capacity (128 KiB LDS -> 1 block/CU, 256 blocks on 256 CUs).
//
// XCD-LOCALIZED domain mapping: MI355X dispatches blockIdx round-robin over
// the 8 XCDs, so xcd = bid&7. Domain dom = xcd>>1 (2 XCDs per domain),
// wg = (xcd&1)*32 + (bid>>3). Each domain's 64 KB/step h-tile then fills
// only 2 L2s and 62/64 WGs stage from local L2 instead of the LLC.
// (Pure bijection -- if placement differs, only speed changes.)
//
// Exchange protocol (no fences):
//  - h stores: relaxed AGENT atomic stores (write-through, no-allocate).
//  - own x_proj cell read: relaxed AGENT atomic 4B load (L1/L2 bypass) so
//    (b,t) lines never enter our caches before peers overwrite them.
//  - ordering: s_waitcnt vmcnt(0) + __syncthreads, then ONE relaxed flag
//    store per WG (own 128B-spaced slot -- parallel LLC lines, no RMW
//    serialization).
//  - consumer: 64 lanes poll the domain's 64 flags (one parallel gather RT)
//    until __all(flag >= t); h_{t-1} then staged with PLAIN cached float4
//    loads (L2-served). Safe: no cache holds a (b,t-1) line from before the
//    sync point.
// ---------------------------------------------------------------------------
__global__ __launch_bounds__(256) void rnn_rec(
    const float* __restrict__ w_rec, const float* __restrict__ b_rec,
    float* __restrict__ hids, unsigned* __restrict__ flags)
{
    __shared__ float Wl[16 * 1024];
    __shared__ float Hl[16 * 1024];
    const int tid = threadIdx.x;
    const int bid = blockIdx.x;
    const int xcd = bid & 7;
    const int dom = xcd >> 1;                  // 0..3
    const int wg  = ((xcd & 1) << 5) | (bid >> 3);  // 0..63
    const int r0 = wg << 4;
    const int b0 = dom << 4;
    // flag layout: 32 uints (128 B) per WG; domain block = 64*32 uints
    unsigned* fl_dom = flags + (dom << 11);
    unsigned* fl_own = fl_dom + (wg << 5);

    // ---- preload W rows r0..r0+15, swizzled: pk = kg ^ ((kg>>3)&7) ^ ((r>>3)<<2)
    {
        const int r = tid >> 4, l = tid & 15;
        const float* src = w_rec + (size_t)(r0 + r) * H_;
        float* dst = Wl + r * 1024;
#pragma unroll
        for (int u = 0; u < 16; ++u) {
            int kg = u * 16 + l;
            float4 v = *(const float4*)(src + kg * 4);
            int pk = kg ^ ((kg >> 3) & 7) ^ ((r >> 3) << 2);
            *(float4*)(dst + pk * 4) = v;
        }
    }

    // epilogue mapping: output o = tid -> (b_local = tid>>4, r_local = tid&15)
    const int bl_e = tid >> 4, rl_e = tid & 15;
    const float brec = b_rec[r0 + rl_e];
    float* xcell = hids + ((size_t)(b0 + bl_e) * T_) * H_ + (r0 + rl_e);

    // compute mapping: tid = ks*8 + rb*4 + bb ; tile 4b x 8r, K split 32 ways
    const int ks = tid >> 3;        // 0..31, k-slice of 32
    const int rb = (tid >> 2) & 1;  // row block (8 rows)
    const int bb = tid & 3;         // batch block (4 batches)
    const int cW = (ks & 7) ^ (rb << 2);
    const int cH = (ks & 7) ^ (bb << 1);
    // reduction read index: un-swizzle the (o ^ bb<<3) scratch layout
    const int rd_idx = tid ^ (((tid >> 6) & 3) << 3);

    __syncthreads();

    for (int t = 0; t < T_; ++t) {
        // own x_proj cell -- BYPASS load (keeps (b,t) lines out of L1/L2)
        float x = __hip_atomic_load(&xcell[(size_t)t * H_], __ATOMIC_RELAXED,
                                    __HIP_MEMORY_SCOPE_AGENT);
        float sum = 0.f;
        if (t > 0) {
            // ---- wait: all 64 WGs of this domain finished step t-1
            if (tid < 64) {
                long long ts = __builtin_amdgcn_s_memrealtime();
                for (;;) {
                    unsigned f = __hip_atomic_load(fl_dom + (tid << 5),
                                                   __ATOMIC_RELAXED,
                                                   __HIP_MEMORY_SCOPE_AGENT);
                    if (__all(f >= (unsigned)t)) break;
                    // ~100ms hang bailout (memrealtime ~100 MHz)
                    if (__builtin_amdgcn_s_memrealtime() - ts > 10000000LL) break;
                }
            }
            __syncthreads();

            // ---- stage h_{t-1}[b0..b0+15][:] into LDS, PLAIN cached float4
            {
                const int blr = tid >> 4, l = tid & 15;
                const float* hsrc = hids + ((size_t)(b0 + blr) * T_ + (t - 1)) * H_;
                float* hdst = Hl + blr * 1024;
#pragma unroll
                for (int u = 0; u < 16; ++u) {
                    int kg = u * 16 + l;
                    float4 v = *(const float4*)(hsrc + kg * 4);
                    int pk = kg ^ ((kg >> 3) & 7) ^ ((blr >> 2) << 1);
                    *(float4*)(hdst + pk * 4) = v;
                }
            }
            __syncthreads();

            // ---- partial dot products over this thread's 32-wide k slice
            float acc[4][8];
#pragma unroll
            for (int i = 0; i < 4; ++i) {
#pragma unroll
                for (int j = 0; j < 8; ++j) acc[i][j] = 0.f;
            }
#pragma unroll
            for (int j4 = 0; j4 < 8; ++j4) {
                const int sW = (j4 ^ cW) << 2;
                const int sH = (j4 ^ cH) << 2;
                float4 hv[4], wv[8];
#pragma unroll
                for (int i = 0; i < 4; ++i)
                    hv[i] = *(const float4*)(Hl + (bb * 4 + i) * 1024 + ks * 32 + sH);
#pragma unroll
                for (int i = 0; i < 8; ++i)
                    wv[i] = *(const float4*)(Wl + (rb * 8 + i) * 1024 + ks * 32 + sW);
#pragma unroll
                for (int bi = 0; bi < 4; ++bi) {
#pragma unroll
                    for (int ri = 0; ri < 8; ++ri) {
                        acc[bi][ri] += hv[bi].x * wv[ri].x + hv[bi].y * wv[ri].y +
                                       hv[bi].z * wv[ri].z + hv[bi].w * wv[ri].w;
                    }
                }
            }
            __syncthreads();  // Hl consumed -> reuse as reduction scratch

            float* scr = Hl;  // [32][259]; write swizzle o^(bb<<3) -> 2-way free
#pragma unroll
            for (int bi = 0; bi < 4; ++bi) {
#pragma unroll
                for (int ri = 0; ri < 8; ++ri) {
                    int o = ((bb * 4 + bi) * 16 + rb * 8 + ri) ^ (bb << 3);
                    scr[ks * 259 + o] = acc[bi][ri];
                }
            }
            __syncthreads();
            float s0 = 0.f, s1 = 0.f, s2 = 0.f, s3 = 0.f;
#pragma unroll
            for (int s = 0; s < 8; ++s) {
                s0 += scr[(4 * s + 0) * 259 + rd_idx];
                s1 += scr[(4 * s + 1) * 259 + rd_idx];
                s2 += scr[(4 * s + 2) * 259 + rd_idx];
                s3 += scr[(4 * s + 3) * 259 + rd_idx];
            }
            sum = (s0 + s1) + (s2 + s3);
        }

        float hnew = fmaxf(sum + brec + x, 0.f);
        // write-through to LLC (relaxed agent atomic store; no-allocate)
        __hip_atomic_store(&xcell[(size_t)t * H_], hnew, __ATOMIC_RELAXED,
                           __HIP_MEMORY_SCOPE_AGENT);

        // per-wave drain, block-wide join, then ONE parallel flag store per WG
        asm volatile("s_waitcnt vmcnt(0)" ::: "memory");
        __syncthreads();
        if (tid == 0)
            __hip_atomic_store(fl_own, (unsigned)(t + 1), __ATOMIC_RELAXED,
                               __HIP_MEMORY_SCOPE_AGENT);
    }
}

// ---------------------------------------------------------------------------
extern "C" void kernel_launch(void* const* d_in, const int* in_sizes, int n_in,
                              void* d_out, int out_size, void* d_ws, size_t ws_size,
                              hipStream_t stream)
{
    const float* inputs = (const float*)d_in[0];
    const float* w_rec  = (const float*)d_in[1];
    const float* b_rec  = (const float*)d_in[2];
    const float* w_in   = (const float*)d_in[3];
    const float* b_in   = (const float*)d_in[4];
    const float* w_out  = (const float*)d_in[5];
    const float* b_out  = (const float*)d_in[6];
    const float* scale  = (const float*)d_in[7];
    const float* shift  = (const float*)d_in[8];

    float* outs = (float*)d_out;                       // [B][T][O]
    float* hids = outs + (size_t)B_ * T_ * O_;         // [B][T][H]
    unsigned* flags = (unsigned*)d_ws;                 // 4 dom x 64 wg x 128B

    hipMemsetAsync(d_ws, 0, 32768, stream);

    // K1: x_proj = inputs @ w_in^T + b_in  -> written into hids region
    gemm_bt<I_, 0><<<dim3((B_ * T_ / 64) * (H_ / 64)), dim3(256), 0, stream>>>(
        inputs, w_in, b_in, nullptr, nullptr, hids, B_ * T_, H_);

    // K2: recurrent scan — plain launch; co-residency by capacity (1 blk/CU x 256)
    rnn_rec<<<dim3(256), dim3(256), 0, stream>>>(w_rec, b_rec, hids, flags);

    // K3: outs = scale * (hids @ w_out^T + b_out) - shift
    gemm_bt<H_, 1><<<dim3((B_ * T_ / 64) * (O_ / 64)), dim3(256), 0, stream>>>(
        hids, w_out, b_out, scale, shift, outs, B_ * T_, O_);
}

// Round 7
// 4403.127 us; speedup vs baseline: 6.0214x; 1.0389x over previous
//
#include <hip/hip_runtime.h>

#define B_ 64
#define T_ 512
#define H_ 1024
#define I_ 256
#define O_ 256

// ---------------------------------------------------------------------------
// Tiled fp32 GEMM:  C[M][N] = A[M][KTOT] . Bw[N][KTOT]^T  (+ epilogue)
// EPI 0: C = acc + bias[n]
// EPI 1: C = scale[n]*(acc + bias[n]) - shift[n]
// ---------------------------------------------------------------------------
template <int KTOT, int EPI>
__global__ __launch_bounds__(256) void gemm_bt(
    const float* __restrict__ A, const float* __restrict__ Bw,
    const float* __restrict__ bias, const float* __restrict__ scale,
    const float* __restrict__ shift, float* __restrict__ C, int M, int N)
{
    __shared__ float As[64][68];
    __shared__ float Bs[64][68];
    const int tid = threadIdx.x;
    const int tx = tid & 15;   // n sub-block
    const int ty = tid >> 4;   // m sub-block
    const int NB = N >> 6;
    const int mblk = blockIdx.x / NB;
    const int nblk = blockIdx.x % NB;
    const int m0 = mblk << 6, n0 = nblk << 6;
    const int NC = KTOT / 64;

    float acc[4][4];
#pragma unroll
    for (int i = 0; i < 4; ++i) {
#pragma unroll
        for (int j = 0; j < 4; ++j) acc[i][j] = 0.f;
    }

    float4 ra[4], rb[4];
#pragma unroll
    for (int i = 0; i < 4; ++i) {
        int r = ty + 16 * i;
        ra[i] = *(const float4*)(A + (size_t)(m0 + r) * KTOT + tx * 4);
        rb[i] = *(const float4*)(Bw + (size_t)(n0 + r) * KTOT + tx * 4);
    }

    for (int c = 0; c < NC; ++c) {
#pragma unroll
        for (int i = 0; i < 4; ++i) {
            int r = ty + 16 * i;
            *(float4*)(&As[r][(tx ^ (r >> 2)) * 4]) = ra[i];
            *(float4*)(&Bs[r][(tx ^ (r >> 2)) * 4]) = rb[i];
        }
        __syncthreads();
        if (c + 1 < NC) {
            int kc = (c + 1) * 64;
#pragma unroll
            for (int i = 0; i < 4; ++i) {
                int r = ty + 16 * i;
                ra[i] = *(const float4*)(A + (size_t)(m0 + r) * KTOT + kc + tx * 4);
                rb[i] = *(const float4*)(Bw + (size_t)(n0 + r) * KTOT + kc + tx * 4);
            }
        }
#pragma unroll
        for (int kg = 0; kg < 16; ++kg) {
            float4 a4[4], b4[4];
#pragma unroll
            for (int i = 0; i < 4; ++i)
                a4[i] = *(const float4*)(&As[4 * ty + i][(kg ^ ty) * 4]);
#pragma unroll
            for (int j = 0; j < 4; ++j)
                b4[j] = *(const float4*)(&Bs[4 * tx + j][(kg ^ tx) * 4]);
#pragma unroll
            for (int i = 0; i < 4; ++i) {
#pragma unroll
                for (int j = 0; j < 4; ++j) {
                    acc[i][j] += a4[i].x * b4[j].x + a4[i].y * b4[j].y +
                                 a4[i].z * b4[j].z + a4[i].w * b4[j].w;
                }
            }
        }
        __syncthreads();
    }

    float4 bi4 = *(const float4*)(bias + n0 + tx * 4);
    float4 sc4, sh4;
    if (EPI == 1) {
        sc4 = *(const float4*)(scale + n0 + tx * 4);
        sh4 = *(const float4*)(shift + n0 + tx * 4);
    }
#pragma unroll
    for (int i = 0; i < 4; ++i) {
        float4 r;
        if (EPI == 0) {
            r.x = acc[i][0] + bi4.x;
            r.y = acc[i][1] + bi4.y;
            r.z = acc[i][2] + bi4.z;
            r.w = acc[i][3] + bi4.w;
        } else {
            r.x = sc4.x * (acc[i][0] + bi4.x) - sh4.x;
            r.y = sc4.y * (acc[i][1] + bi4.y) - sh4.y;
            r.z = sc4.z * (acc[i][2] + bi4.z) - sh4.z;
            r.w = sc4.w * (acc[i][3] + bi4.w) - sh4.w;
        }
        *(float4*)(C + (size_t)(m0 + 4 * ty + i) * N + n0 + 4 * tx) = r;
    }
}

// ---------------------------------------------------------------------------
// Recurrent kernel. 256 blocks x 256 threads, plain launch; co-residency by
// capacity (128 KiB LDS -> 1 block/CU, 256 blocks on 256 CUs).
//
// XCD-localized mapping: xcd = bid&7 (round-robin dispatch), dom = xcd>>1,
// wg = (xcd&1)*32 + (bid>>3): each domain on 2 XCDs (verified r6: FETCH
// 658->226 MB).
//
// Exchange protocol:
//  - h stores: atomicExch (returning) -> executes AT the LLC and leaves the
//    line ALLOCATED there (plain relaxed atomic stores proved non-temporal:
//    r6 FETCH_SIZE showed h staging re-fetched from HBM every step).
//  - own x_proj cell read: relaxed AGENT atomic 4B load (L1/L2 bypass) so
//    (b,t) lines never enter our caches before peers overwrite them.
//  - ordering: s_waitcnt vmcnt(0) (drains the returning atomics) +
//    __syncthreads, then ONE relaxed flag store per WG (own 128B slot).
//  - consumer: WAVE-LOCAL wait. Wave v stages h columns [256v,256v+256),
//    which are produced by WGs 16v..16v+15 only -> poll those 16 flags,
//    then stage immediately (no block barrier; staging regions disjoint per
//    wave under the XOR swizzle). One __syncthreads before compute.
//    Staging uses PLAIN cached float4 loads: L2 hit after first LLC fill.
// ---------------------------------------------------------------------------
__global__ __launch_bounds__(256) void rnn_rec(
    const float* __restrict__ w_rec, const float* __restrict__ b_rec,
    float* __restrict__ hids, unsigned* __restrict__ flags)
{
    __shared__ float Wl[16 * 1024];
    __shared__ float Hl[16 * 1024];
    const int tid = threadIdx.x;
    const int bid = blockIdx.x;
    const int xcd = bid & 7;
    const int dom = xcd >> 1;                  // 0..3
    const int wg  = ((xcd & 1) << 5) | (bid >> 3);  // 0..63
    const int r0 = wg << 4;
    const int b0 = dom << 4;
    // flag layout: 32 uints (128 B) per WG; domain block = 64*32 uints
    unsigned* fl_dom = flags + (dom << 11);
    unsigned* fl_own = fl_dom + (wg << 5);

    // ---- preload W rows r0..r0+15, swizzled: pk = kg ^ ((kg>>3)&7) ^ ((r>>3)<<2)
    {
        const int r = tid >> 4, l = tid & 15;
        const float* src = w_rec + (size_t)(r0 + r) * H_;
        float* dst = Wl + r * 1024;
#pragma unroll
        for (int u = 0; u < 16; ++u) {
            int kg = u * 16 + l;
            float4 v = *(const float4*)(src + kg * 4);
            int pk = kg ^ ((kg >> 3) & 7) ^ ((r >> 3) << 2);
            *(float4*)(dst + pk * 4) = v;
        }
    }

    // epilogue mapping: output o = tid -> (b_local = tid>>4, r_local = tid&15)
    const int bl_e = tid >> 4, rl_e = tid & 15;
    const float brec = b_rec[r0 + rl_e];
    float* xcell = hids + ((size_t)(b0 + bl_e) * T_) * H_ + (r0 + rl_e);

    // compute mapping: tid = ks*8 + rb*4 + bb ; tile 4b x 8r, K split 32 ways
    const int ks = tid >> 3;        // 0..31, k-slice of 32
    const int rb = (tid >> 2) & 1;  // row block (8 rows)
    const int bb = tid & 3;         // batch block (4 batches)
    const int cW = (ks & 7) ^ (rb << 2);
    const int cH = (ks & 7) ^ (bb << 1);
    // reduction read index: un-swizzle the (o ^ bb<<3) scratch layout
    const int rd_idx = tid ^ (((tid >> 6) & 3) << 3);

    // staging mapping (wave-column): wave v stages col-groups [64v, 64v+64)
    const int wv = tid >> 6;                 // wave 0..3
    const int lane = tid & 63;
    const int kgS = (wv << 6) | lane;        // column group 0..255
    const int pk0 = kgS ^ ((kgS >> 3) & 7);  // swizzle base (u-part added later)
    const unsigned* fl_poll = fl_dom + (((wv << 4) | (lane & 15)) << 5);

    __syncthreads();

    for (int t = 0; t < T_; ++t) {
        // own x_proj cell -- BYPASS load (keeps (b,t) lines out of L1/L2)
        float x = __hip_atomic_load(&xcell[(size_t)t * H_], __ATOMIC_RELAXED,
                                    __HIP_MEMORY_SCOPE_AGENT);
        float sum = 0.f;
        if (t > 0) {
            // ---- wave-local wait: only the 16 producers of our columns
            {
                long long ts = __builtin_amdgcn_s_memrealtime();
                for (;;) {
                    unsigned f = __hip_atomic_load(fl_poll, __ATOMIC_RELAXED,
                                                   __HIP_MEMORY_SCOPE_AGENT);
                    if (__all(f >= (unsigned)t)) break;
                    // ~100ms hang bailout (memrealtime ~100 MHz)
                    if (__builtin_amdgcn_s_memrealtime() - ts > 10000000LL) break;
                }
            }

            // ---- stage our 256-float column slice for all 16 batches
            {
                const float* hs = hids + ((size_t)b0 * T_ + (t - 1)) * H_ + (kgS << 2);
#pragma unroll
                for (int u = 0; u < 16; ++u) {
                    float4 v = *(const float4*)(hs + (size_t)u * T_ * H_);
                    int pk = pk0 ^ ((u >> 2) << 1);
                    *(float4*)(Hl + u * 1024 + pk * 4) = v;
                }
            }
            __syncthreads();  // all waves' columns staged

            // ---- partial dot products over this thread's 32-wide k slice
            float acc[4][8];
#pragma unroll
            for (int i = 0; i < 4; ++i) {
#pragma unroll
                for (int j = 0; j < 8; ++j) acc[i][j] = 0.f;
            }
#pragma unroll
            for (int j4 = 0; j4 < 8; ++j4) {
                const int sW = (j4 ^ cW) << 2;
                const int sH = (j4 ^ cH) << 2;
                float4 hv[4], wv8[8];
#pragma unroll
                for (int i = 0; i < 4; ++i)
                    hv[i] = *(const float4*)(Hl + (bb * 4 + i) * 1024 + ks * 32 + sH);
#pragma unroll
                for (int i = 0; i < 8; ++i)
                    wv8[i] = *(const float4*)(Wl + (rb * 8 + i) * 1024 + ks * 32 + sW);
#pragma unroll
                for (int bi = 0; bi < 4; ++bi) {
#pragma unroll
                    for (int ri = 0; ri < 8; ++ri) {
                        acc[bi][ri] += hv[bi].x * wv8[ri].x + hv[bi].y * wv8[ri].y +
                                       hv[bi].z * wv8[ri].z + hv[bi].w * wv8[ri].w;
                    }
                }
            }
            __syncthreads();  // Hl consumed -> reuse as reduction scratch

            float* scr = Hl;  // [32][259]; write swizzle o^(bb<<3) -> 2-way free
#pragma unroll
            for (int bi = 0; bi < 4; ++bi) {
#pragma unroll
                for (int ri = 0; ri < 8; ++ri) {
                    int o = ((bb * 4 + bi) * 16 + rb * 8 + ri) ^ (bb << 3);
                    scr[ks * 259 + o] = acc[bi][ri];
                }
            }
            __syncthreads();
            float s0 = 0.f, s1 = 0.f, s2 = 0.f, s3 = 0.f;
#pragma unroll
            for (int s = 0; s < 8; ++s) {
                s0 += scr[(4 * s + 0) * 259 + rd_idx];
                s1 += scr[(4 * s + 1) * 259 + rd_idx];
                s2 += scr[(4 * s + 2) * 259 + rd_idx];
                s3 += scr[(4 * s + 3) * 259 + rd_idx];
            }
            sum = (s0 + s1) + (s2 + s3);
        }

        float hnew = fmaxf(sum + brec + x, 0.f);
        // LLC-ALLOCATING store: atomicExch executes at the LLC and leaves the
        // line resident there (returning variant; result kept alive).
        float old = __hip_atomic_exchange(&xcell[(size_t)t * H_], hnew,
                                          __ATOMIC_RELAXED,
                                          __HIP_MEMORY_SCOPE_AGENT);
        asm volatile("" :: "v"(old));

        // drain (returning atomic -> vmcnt), block-wide join, then flag store
        asm volatile("s_waitcnt vmcnt(0)" ::: "memory");
        __syncthreads();
        if (tid == 0)
            __hip_atomic_store(fl_own, (unsigned)(t + 1), __ATOMIC_RELAXED,
                               __HIP_MEMORY_SCOPE_AGENT);
    }
}

// ---------------------------------------------------------------------------
extern "C" void kernel_launch(void* const* d_in, const int* in_sizes, int n_in,
                              void* d_out, int out_size, void* d_ws, size_t ws_size,
                              hipStream_t stream)
{
    const float* inputs = (const float*)d_in[0];
    const float* w_rec  = (const float*)d_in[1];
    const float* b_rec  = (const float*)d_in[2];
    const float* w_in   = (const float*)d_in[3];
    const float* b_in   = (const float*)d_in[4];
    const float* w_out  = (const float*)d_in[5];
    const float* b_out  = (const float*)d_in[6];
    const float* scale  = (const float*)d_in[7];
    const float* shift  = (const float*)d_in[8];

    float* outs = (float*)d_out;                       // [B][T][O]
    float* hids = outs + (size_t)B_ * T_ * O_;         // [B][T][H]
    unsigned* flags = (unsigned*)d_ws;                 // 4 dom x 64 wg x 128B

    hipMemsetAsync(d_ws, 0, 32768, stream);

    // K1: x_proj = inputs @ w_in^T + b_in  -> written into hids region
    gemm_bt<I_, 0><<<dim3((B_ * T_ / 64) * (H_ / 64)), dim3(256), 0, stream>>>(
        inputs, w_in, b_in, nullptr, nullptr, hids, B_ * T_, H_);

    // K2: recurrent scan — plain launch; co-residency by capacity (1 blk/CU x 256)
    rnn_rec<<<dim3(256), dim3(256), 0, stream>>>(w_rec, b_rec, hids, flags);

    // K3: outs = scale * (hids @ w_out^T + b_out) - shift
    gemm_bt<H_, 1><<<dim3((B_ * T_ / 64) * (O_ / 64)), dim3(256), 0, stream>>>(
        hids, w_out, b_out, scale, shift, outs, B_ * T_, O_);
}